// Round 8
// baseline (5949.977 us; speedup 1.0000x reference)
//
#include <hip/hip_runtime.h>

// TrajLSTM: 2-layer LSTM (H=1024), T=64 steps + 16 autoregressive. B=1024, I=64.
// fp16 MFMA GEMMs, fused LSTM-cell epilogue, fp16-MFMA out-proj.
//
// State rows (fp16, stride 2176): [h1(1024) | x(64) | pad(64) | h2(1024)],
// three buffers rotating by t%3; one fused main dispatch = {L2(t), L1(t+1),
// proj(t-1), xcopy(t+2)}. Future phase: composed L1' (proj folded into L1).
//
// Round 8: BARRIER-FREE K-loop, direct VGPR streaming.
//  - A-fragments loaded straight from the row-major state with per-lane
//    global_load_dwordx4 (lanes lq=0..3 of a row cover one 64B line - no
//    waste); B from packed fragment chunks. No LDS staging, no DMA, no
//    per-iter barriers -> per-wave latency hidden by other waves instead of
//    block-wide vmcnt(0) drains (the r4-r7 plateau).
//  - Fully-unrolled templated K-loop (ITERS=16/9): immediate offsets, SSA
//    double-buffered prefetch (no register copies).
//  - LDS = 16 KB split-K combine scratch only; __launch_bounds__(256,2).
//  - compose_pack (61 us scalar) -> compose_tile (LDS-tiled, ~4 us), writes
//    packed W1c2 composite half directly; Whh1 half moved into convert_all.

#define B_   1024
#define T_   64
#define I_   64
#define H_   1024
#define FUT_ 16
#define NST_ (T_ + FUT_)
#define SROW 2176

typedef _Float16 half8_t  __attribute__((ext_vector_type(8)));
typedef float    float4_t __attribute__((ext_vector_type(4)));

typedef __attribute__((address_space(1))) const unsigned int g_u32;
typedef __attribute__((address_space(3))) unsigned int l_u32;

__device__ __forceinline__ void load_lds16(const _Float16* g, _Float16* l) {
    __builtin_amdgcn_global_load_lds((g_u32*)g, (l_u32*)l, 16, 0, 0);
}

__device__ __forceinline__ float sigmoid_f(float x) {
    x = fminf(fmaxf(x, -30.f), 30.f);
    return __fdividef(1.f, 1.f + __expf(-x));
}
__device__ __forceinline__ float tanh_f(float x) {
    x = fminf(fmaxf(x, -15.f), 15.f);
    float e = __expf(2.f * x);
    return 1.f - 2.f * __fdividef(1.f, e + 1.f);
}

// ---------------- one-time conversion / packing ----------------------------
// W1p:  [hgrp 64][kstep 36][gate 4][1KB]  (K=1152: Whh1 | Wih1 | pad0)
// W2p:  [hgrp 64][kstep 64][gate 4][1KB]  (K=2048: Wih2 | Whh2)
// W1c2: [hgrp 64][kstep 64][gate 4][1KB]  (K=2048: Whh1 | Wih1@Wlin) - low
//       half (j<32, Whh1) written here; high half by compose_tile.
// Wlp:  [hgrp 4 ][kstep 32][1KB]          (64 x 1024)
__global__ void convert_all(const float* __restrict__ x,
    const float* __restrict__ Wih1, const float* __restrict__ Whh1,
    const float* __restrict__ bih1, const float* __restrict__ bhh1,
    const float* __restrict__ Wih2, const float* __restrict__ Whh2,
    const float* __restrict__ bih2, const float* __restrict__ bhh2,
    const float* __restrict__ Wlin,
    _Float16* __restrict__ W1p, _Float16* __restrict__ W2p,
    _Float16* __restrict__ W1c2, _Float16* __restrict__ Wlp,
    _Float16* __restrict__ S0x, _Float16* __restrict__ S1x,
    float* __restrict__ b1, float* __restrict__ b2)
{
    size_t idx = (size_t)blockIdx.x * 256 + threadIdx.x;
    const size_t nc1  = 589824;    // 4096*1152/8
    const size_t nc2  = 1048576;   // 4096*2048/8
    const size_t nc2b = 524288;    // W1c2 low half: 64*32*4*64
    const size_t nc3  = 8192;      // 64*1024/8
    const size_t nx   = 65536;     // B_*I_
    if (idx < nc1) {
        int c = (int)idx;
        int lane = c & 63, g = (c >> 6) & 3, rem = c >> 8;
        int j = rem % 36, hgrp = rem / 36;
        int row = (g << 10) + hgrp * 16 + (lane & 15);
        int kb = j * 32 + (lane >> 4) * 8;
        _Float16* o = &W1p[(size_t)c * 8];
        if (kb < 1024) {
            #pragma unroll
            for (int i = 0; i < 8; ++i) o[i] = (_Float16)Whh1[(size_t)row * 1024 + kb + i];
        } else if (kb < 1088) {
            #pragma unroll
            for (int i = 0; i < 8; ++i) o[i] = (_Float16)Wih1[row * 64 + (kb - 1024) + i];
        } else {
            #pragma unroll
            for (int i = 0; i < 8; ++i) o[i] = (_Float16)0.f;
        }
    } else if ((idx -= nc1) < nc2) {
        int c = (int)idx;
        int lane = c & 63, g = (c >> 6) & 3, rem = c >> 8;
        int j = rem & 63, hgrp = rem >> 6;
        int row = (g << 10) + hgrp * 16 + (lane & 15);
        int kb = j * 32 + (lane >> 4) * 8;
        _Float16* o = &W2p[(size_t)c * 8];
        if (kb < 1024) {
            #pragma unroll
            for (int i = 0; i < 8; ++i) o[i] = (_Float16)Wih2[(size_t)row * 1024 + kb + i];
        } else {
            #pragma unroll
            for (int i = 0; i < 8; ++i) o[i] = (_Float16)Whh2[(size_t)row * 1024 + kb - 1024 + i];
        }
    } else if ((idx -= nc2) < nc2b) {
        int c = (int)idx;
        int lane = c & 63, g = (c >> 6) & 3, rem = c >> 8;
        int j = rem & 31, hgrp = rem >> 5;
        int row = (g << 10) + hgrp * 16 + (lane & 15);
        int kb = j * 32 + (lane >> 4) * 8;
        _Float16* o = &W1c2[((((size_t)hgrp * 64 + j) * 4 + g) * 512) + lane * 8];
        #pragma unroll
        for (int i = 0; i < 8; ++i) o[i] = (_Float16)Whh1[(size_t)row * 1024 + kb + i];
    } else if ((idx -= nc2b) < nc3) {
        int c = (int)idx;
        int lane = c & 63, j = (c >> 6) & 31, hgrp = c >> 11;
        int row = hgrp * 16 + (lane & 15);
        int kb = j * 32 + (lane >> 4) * 8;
        _Float16* o = &Wlp[(size_t)c * 8];
        #pragma unroll
        for (int i = 0; i < 8; ++i) o[i] = (_Float16)Wlin[(size_t)row * 1024 + kb + i];
    } else if ((idx -= nc3) < nx) {
        int b = (int)(idx >> 6), i = (int)(idx & 63);
        S0x[(size_t)b * SROW + i] = (_Float16)x[(size_t)b * (T_ * I_) + i];
    } else if ((idx -= nx) < nx) {
        int b = (int)(idx >> 6), i = (int)(idx & 63);
        S1x[(size_t)b * SROW + i] = (_Float16)x[(size_t)b * (T_ * I_) + 64 + i];
    } else if ((idx -= nx) < 4096) {
        b1[idx] = bih1[idx] + bhh1[idx];
    } else if ((idx -= 4096) < 4096) {
        b2[idx] = bih2[idx] + bhh2[idx];
    }
}

// Composite = Wih1(4096x64) @ Wlin(64x1024), LDS-tiled, packed fp16 output
// into W1c2 high half (j>=32). Blocks >=1024 compute bc1 = b1 + Wih1@b_lin.
__global__ __launch_bounds__(256) void compose_tile(
    const float* __restrict__ Wih1, const float* __restrict__ Wlin,
    const float* __restrict__ blin, const float* __restrict__ b1in,
    _Float16* __restrict__ W1c2, float* __restrict__ bc1)
{
    if (blockIdx.x >= 1024) {
        int n = (blockIdx.x - 1024) * 256 + threadIdx.x;   // 0..4095
        float s = b1in[n];
        for (int i = 0; i < 64; ++i) s += Wih1[n * 64 + i] * blin[i];
        bc1[n] = s;
        return;
    }
    __shared__ float sa[64][68];
    __shared__ float swl[64][68];
    const int tid = threadIdx.x;
    const int r0 = (blockIdx.x >> 4) * 64, c0 = (blockIdx.x & 15) * 64;
    #pragma unroll
    for (int t = 0; t < 16; ++t) {
        int e = tid + t * 256;
        int rr = e >> 6, cc = e & 63;
        sa[rr][cc]  = Wih1[(size_t)(r0 + rr) * 64 + cc];
        swl[rr][cc] = Wlin[(size_t)rr * 1024 + c0 + cc];
    }
    __syncthreads();
    const int tr = (tid >> 3) * 2, tc = (tid & 7) * 8;
    float acc[2][8] = {};
    for (int k = 0; k < 64; ++k) {
        float a0 = sa[tr][k], a1 = sa[tr + 1][k];
        #pragma unroll
        for (int j = 0; j < 8; ++j) {
            float wv = swl[k][tc + j];
            acc[0][j] += a0 * wv;
            acc[1][j] += a1 * wv;
        }
    }
    #pragma unroll
    for (int rr = 0; rr < 2; ++rr) {
        const int row = r0 + tr + rr;
        const int g = row >> 10, hgrp = (row & 1023) >> 4, lr16 = row & 15;
        const int hcol = c0 + tc;
        const int j = 32 + (hcol >> 5), lq = (hcol >> 3) & 3;
        half8_t v;
        #pragma unroll
        for (int e2 = 0; e2 < 8; ++e2) v[e2] = (_Float16)acc[rr][e2];
        *(half8_t*)(W1c2 + ((((size_t)hgrp * 64 + j) * 4 + g) * 512
                    + (lq * 16 + lr16) * 8)) = v;
    }
}

// ---------------- GEMM + fused LSTM cell (barrier-free K-loop) -------------
// Block tile: 64 batch x 32 H x 4 gates; 4 waves = 2 hw (H) x 2 kh (split-K).
// K-loop: A and B stream global->VGPR, fully unrolled, SSA dbuf prefetch.
template<int ITERS>
__device__ __forceinline__ void gemm_body(float* scr,
    const _Float16* __restrict__ Alo, const _Float16* __restrict__ Ahi,
    const _Float16* __restrict__ Wp,
    const float* __restrict__ bias, float* __restrict__ cvec,
    _Float16* __restrict__ hdst, const int unit)
{
    constexpr int KSH = 2 * ITERS;
    const int tid = threadIdx.x;
    const int lane = tid & 63, w = tid >> 6;
    const int hw = w & 1, kh = w >> 1;
    const int lr = lane & 15, lq = lane >> 4;
    const int ht = ((unit & 7) << 2) | ((unit >> 3) & 3);   // XCD-pinned H tile
    const int mt = unit >> 5;
    const int h0 = ht * 32, m0 = mt * 64;
    const int hgrp = ht * 2 + hw;

    // B: packed chunk stream for this wave's (hgrp, K-half)
    const char* wptr = (const char*)Wp
        + ((size_t)hgrp * (2 * KSH) + (size_t)kh * KSH) * 4096;
    // A: per-lane row pointer; lane covers (row m0+rt*16+lr, k lq*8..+8)
    const _Float16* aptr0 = (kh ? Ahi : Alo)
        + (size_t)(m0 + lr) * SROW + lq * 8;

    float4_t acc[4][4];
    #pragma unroll
    for (int g = 0; g < 4; ++g)
        #pragma unroll
        for (int rt = 0; rt < 4; ++rt)
            #pragma unroll
            for (int e = 0; e < 4; ++e) acc[g][rt][e] = 0.f;

    half8_t af[2][2][4], bf[2][8];
    #pragma unroll
    for (int ks = 0; ks < 2; ++ks)
        #pragma unroll
        for (int rt = 0; rt < 4; ++rt)
            af[0][ks][rt] = *(const half8_t*)(aptr0
                + (size_t)rt * 16 * SROW + ks * 32);
    #pragma unroll
    for (int q = 0; q < 8; ++q)
        bf[0][q] = *(const half8_t*)(wptr + q * 1024 + lane * 16);

    #pragma unroll
    for (int i = 0; i < ITERS; ++i) {
        const int cur = i & 1, nxt = cur ^ 1;
        if (i + 1 < ITERS) {
            #pragma unroll
            for (int ks = 0; ks < 2; ++ks)
                #pragma unroll
                for (int rt = 0; rt < 4; ++rt)
                    af[nxt][ks][rt] = *(const half8_t*)(aptr0
                        + (size_t)rt * 16 * SROW + (i + 1) * 64 + ks * 32);
            #pragma unroll
            for (int q = 0; q < 8; ++q)
                bf[nxt][q] = *(const half8_t*)(wptr
                    + (size_t)(i + 1) * 8192 + q * 1024 + lane * 16);
        }
        #pragma unroll
        for (int ks = 0; ks < 2; ++ks)
            #pragma unroll
            for (int rt = 0; rt < 4; ++rt)
                #pragma unroll
                for (int g = 0; g < 4; ++g)
                    acc[g][rt] = __builtin_amdgcn_mfma_f32_16x16x32_f16(
                        af[cur][ks][rt], bf[cur][ks * 4 + g], acc[g][rt], 0, 0, 0);
    }

    // split-K combine through LDS (2 rounds x 2 gates, 16 KB scratch)
    #pragma unroll
    for (int gp = 0; gp < 2; ++gp) {
        __syncthreads();
        if (kh == 1) {
            #pragma unroll
            for (int g2 = 0; g2 < 2; ++g2)
                #pragma unroll
                for (int rt = 0; rt < 4; ++rt) {
                    int slot = ((hw * 2 + g2) * 4 + rt) * 64 + lane;
                    *(float4_t*)&scr[slot * 4] = acc[gp * 2 + g2][rt];
                }
        }
        __syncthreads();
        if (kh == 0) {
            #pragma unroll
            for (int g2 = 0; g2 < 2; ++g2)
                #pragma unroll
                for (int rt = 0; rt < 4; ++rt) {
                    int slot = ((hw * 2 + g2) * 4 + rt) * 64 + lane;
                    acc[gp * 2 + g2][rt] += *(const float4_t*)&scr[slot * 4];
                }
        }
    }
    if (kh != 0) return;

    const int j = h0 + hw * 16 + lr;
    const float bi = bias[j], bff = bias[1024 + j];
    const float bg = bias[2048 + j], bo = bias[3072 + j];
    #pragma unroll
    for (int rt = 0; rt < 4; ++rt) {
        #pragma unroll
        for (int e = 0; e < 4; ++e) {
            const int brow = m0 + rt * 16 + lq * 4 + e;
            float gi = sigmoid_f(acc[0][rt][e] + bi);
            float gf = sigmoid_f(acc[1][rt][e] + bff);
            float gv = tanh_f(acc[2][rt][e] + bg);
            float go = sigmoid_f(acc[3][rt][e] + bo);
            const size_t ci = (size_t)brow * 1024 + j;
            float cn = gf * cvec[ci] + gi * gv;
            cvec[ci] = cn;
            hdst[(size_t)brow * SROW + j] = (_Float16)(go * tanh_f(cn));
        }
    }
}

// out-proj: 64 batch x 32 i tile, K=1024 fp16 MFMA (16 KB LDS staging).
__device__ __forceinline__ void proj_body(_Float16* sA,
    const _Float16* __restrict__ A, const _Float16* __restrict__ Wp,
    const float* __restrict__ blin, float* __restrict__ outp,
    const int unit)
{
    const int iters = 8;
    const int tid = threadIdx.x;
    const int lane = tid & 63, w = tid >> 6;
    const int hw = w & 1, kh = w >> 1;
    const int lr = lane & 15, lq = lane >> 4;
    const int ht = unit & 1, mt = unit >> 1;
    const int h0 = ht * 32, m0 = mt * 64;
    const int hgrp = ht * 2 + hw;

    const char* wptr = (const char*)Wp
        + ((size_t)hgrp * 32 + (size_t)kh * 16) * 1024 + (size_t)lane * 16;

    const int srow0 = tid >> 4, pg = tid & 15;
    const int gg = pg ^ (srow0 & 15);
    const _Float16* asrc = A + (size_t)(gg >> 3) * 512 + (gg & 7) * 8
                         + (size_t)(m0 + srow0) * SROW;
    _Float16* ldst = sA + tid * 8;
    const int ag0 = ((kh * 8 + lq) ^ lr) * 8;
    const int ag1 = ((kh * 8 + 4 + lq) ^ lr) * 8;

    float4_t acc[4];
    #pragma unroll
    for (int rt = 0; rt < 4; ++rt)
        #pragma unroll
        for (int e = 0; e < 4; ++e) acc[rt][e] = 0.f;

    half8_t b0 = *(const half8_t*)(wptr);
    half8_t b1v = *(const half8_t*)(wptr + 1024);
    for (int i = 0; i < iters; ++i) {
        #pragma unroll
        for (int s = 0; s < 4; ++s)
            load_lds16(asrc + (size_t)s * 16 * SROW + (size_t)i * 64,
                       ldst + s * 2048);
        __syncthreads();
        half8_t n0, n1;
        if (i + 1 < iters) {
            n0 = *(const half8_t*)(wptr + 2048);
            n1 = *(const half8_t*)(wptr + 3072);
        }
        half8_t af;
        #pragma unroll
        for (int rt = 0; rt < 4; ++rt) {
            af = *(const half8_t*)&sA[(rt * 16 + lr) * 128 + ag0];
            acc[rt] = __builtin_amdgcn_mfma_f32_16x16x32_f16(af, b0, acc[rt], 0, 0, 0);
        }
        #pragma unroll
        for (int rt = 0; rt < 4; ++rt) {
            af = *(const half8_t*)&sA[(rt * 16 + lr) * 128 + ag1];
            acc[rt] = __builtin_amdgcn_mfma_f32_16x16x32_f16(af, b1v, acc[rt], 0, 0, 0);
        }
        __syncthreads();
        wptr += 2048;
        b0 = n0; b1v = n1;
    }

    float* scr = (float*)sA;
    if (kh == 1) {
        #pragma unroll
        for (int rt = 0; rt < 4; ++rt) {
            int slot = (hw * 4 + rt) * 64 + lane;
            *(float4_t*)&scr[slot * 4] = acc[rt];
        }
    }
    __syncthreads();
    if (kh != 0) return;
    #pragma unroll
    for (int rt = 0; rt < 4; ++rt) {
        int slot = (hw * 4 + rt) * 64 + lane;
        acc[rt] += *(const float4_t*)&scr[slot * 4];
    }

    const int j = h0 + hw * 16 + lr;
    const float bj = blin[j];
    #pragma unroll
    for (int rt = 0; rt < 4; ++rt) {
        #pragma unroll
        for (int e = 0; e < 4; ++e) {
            const int brow = m0 + rt * 16 + lq * 4 + e;
            outp[(size_t)brow * (NST_ * I_) + j] = acc[rt][e] + bj;
        }
    }
}

// ---------------- fused multi-role dispatch --------------------------------
struct StepArgs {
    int nL2, nL1, nProj, nCopy, l1Mode;
    const _Float16 *l2Alo, *l2Ahi; _Float16* l2H;
    const _Float16 *l1Alo, *l1Ahi; _Float16* l1H;
    const _Float16* l1W; const float* l1b;
    const _Float16* pA; float* pOut;
    const float* xsrc; _Float16* xdst;
    const _Float16 *W2p, *Wlp;
    const float *b2, *blin;
    float *c1, *c2;
};

__global__ __launch_bounds__(256, 2) void fused_step(StepArgs a) {
    __shared__ __align__(16) char smem[16384];
    int bid = blockIdx.x;
    if (bid < a.nL2) {
        gemm_body<16>((float*)smem, a.l2Alo, a.l2Ahi, a.W2p,
                      a.b2, a.c2, a.l2H, bid);
    } else if ((bid -= a.nL2) < a.nL1) {
        if (a.l1Mode)
            gemm_body<16>((float*)smem, a.l1Alo, a.l1Ahi, a.l1W,
                          a.l1b, a.c1, a.l1H, bid);
        else
            gemm_body<9>((float*)smem, a.l1Alo, a.l1Ahi, a.l1W,
                         a.l1b, a.c1, a.l1H, bid);
    } else if ((bid -= a.nL1) < a.nProj) {
        proj_body((_Float16*)smem, a.pA, a.Wlp, a.blin, a.pOut, bid);
    } else {
        bid -= a.nProj;
        int base = bid * 256 + threadIdx.x;
        for (int k = base; k < B_ * I_; k += a.nCopy * 256) {
            int b = k >> 6, i = k & 63;
            a.xdst[(size_t)b * SROW + i] = (_Float16)a.xsrc[(size_t)b * (T_ * I_) + i];
        }
    }
}

// ---------------------------------------------------------------------------
extern "C" void kernel_launch(void* const* d_in, const int* in_sizes, int n_in,
                              void* d_out, int out_size, void* d_ws, size_t ws_size,
                              hipStream_t stream) {
    (void)in_sizes; (void)n_in; (void)out_size; (void)ws_size;
    const float* x    = (const float*)d_in[0];
    const float* Wih1 = (const float*)d_in[1];
    const float* Whh1 = (const float*)d_in[2];
    const float* bih1 = (const float*)d_in[3];
    const float* bhh1 = (const float*)d_in[4];
    const float* Wih2 = (const float*)d_in[5];
    const float* Whh2 = (const float*)d_in[6];
    const float* bih2 = (const float*)d_in[7];
    const float* bhh2 = (const float*)d_in[8];
    const float* Wlin = (const float*)d_in[9];
    const float* blin = (const float*)d_in[10];
    float* out = (float*)d_out;

    char* p = (char*)d_ws;
    auto alloc = [&](size_t bytes) {
        char* r = p; p += (bytes + 255) & ~(size_t)255; return r;
    };
    _Float16* W1p  = (_Float16*)alloc((size_t)4096 * 1152 * 2);
    _Float16* W2p  = (_Float16*)alloc((size_t)4096 * 2048 * 2);
    _Float16* W1c2 = (_Float16*)alloc((size_t)4096 * 2048 * 2);
    _Float16* Wlp  = (_Float16*)alloc((size_t)64 * 1024 * 2);
    _Float16* S[3];
    for (int i = 0; i < 3; ++i) S[i] = (_Float16*)alloc((size_t)B_ * SROW * 2);
    float* c1  = (float*)alloc((size_t)B_ * H_ * 4);
    float* c2  = (float*)alloc((size_t)B_ * H_ * 4);
    float* b1  = (float*)alloc(4096 * 4);
    float* b2  = (float*)alloc(4096 * 4);
    float* bc1 = (float*)alloc(4096 * 4);

    for (int i = 0; i < 3; ++i)
        hipMemsetAsync(S[i], 0, (size_t)B_ * SROW * 2, stream);
    hipMemsetAsync(c1, 0, (size_t)B_ * H_ * 4, stream);
    hipMemsetAsync(c2, 0, (size_t)B_ * H_ * 4, stream);

    {
        const size_t total = 589824 + 1048576 + 524288 + 8192
                           + 65536 + 65536 + 8192;
        convert_all<<<(int)((total + 255) / 256), 256, 0, stream>>>(
            x, Wih1, Whh1, bih1, bhh1, Wih2, Whh2, bih2, bhh2, Wlin,
            W1p, W2p, W1c2, Wlp, S[0] + 1024, S[1] + 1024, b1, b2);
        compose_tile<<<1040, 256, 0, stream>>>(Wih1, Wlin, blin, b1, W1c2, bc1);
    }

    StepArgs a{};
    a.W2p = W2p; a.Wlp = Wlp; a.blin = blin;
    a.b2 = b2; a.c1 = c1; a.c2 = c2;
    a.l1W = W1p; a.l1b = b1; a.l1Mode = 0;

    // prologue: L1(0) alone (reads S[0] = [0|x(0)], writes h1(0) -> S[1])
    {
        StepArgs q = a;
        q.nL2 = 0; q.nL1 = 512; q.nProj = 0; q.nCopy = 0;
        q.l1Alo = S[0]; q.l1Ahi = S[0] + 576; q.l1H = S[1];
        fused_step<<<512, 256, 0, stream>>>(q);
    }

    // main phase: D_t = {L2(t), L1(t+1), proj(t-1), xcopy(t+2)}
    for (int t = 0; t <= 62; ++t) {
        _Float16* Sp = S[t % 3];
        _Float16* Sq = S[(t + 1) % 3];
        _Float16* Sn = S[(t + 2) % 3];
        StepArgs q = a;
        q.nL2 = 512; q.nL1 = 512;
        q.nProj = (t >= 1) ? 32 : 0;
        q.nCopy = (t <= 61) ? 16 : 0;
        q.l2Alo = Sq; q.l2Ahi = Sp + 1152; q.l2H = Sq + 1152;
        q.l1Alo = Sq; q.l1Ahi = Sq + 576; q.l1H = Sn;
        q.pA = Sp + 1152; q.pOut = out + (size_t)(t - 1) * I_;
        q.xsrc = x + (size_t)(t + 2) * I_; q.xdst = Sn + 1024;
        int grid = q.nL2 + q.nL1 + q.nProj + q.nCopy;
        fused_step<<<grid, 256, 0, stream>>>(q);
    }

    // t=63: {L2(63), proj(62)}
    {
        StepArgs q = a;
        q.nL2 = 512; q.nL1 = 0; q.nProj = 32; q.nCopy = 0;
        q.l2Alo = S[1]; q.l2Ahi = S[0] + 1152; q.l2H = S[1] + 1152;
        q.pA = S[0] + 1152; q.pOut = out + (size_t)62 * I_;
        fused_step<<<544, 256, 0, stream>>>(q);
    }

    // future phase (composed L1'): step t:
    //   D1 = {L1'(t): [h1(t-1)|h2(t-1)] @ W1c2 -> h1(t), proj(t-1)}
    //   D2 = {L2(t):  [h1(t)|h2(t-1)] -> h2(t)}
    for (int t = T_; t < NST_; ++t) {
        _Float16* Sp = S[1 + ((t - T_) & 1)];
        _Float16* Sq = S[1 + (((t - T_) & 1) ^ 1)];
        {
            StepArgs q = a;
            q.nL2 = 0; q.nL1 = 512; q.nProj = 32; q.nCopy = 0;
            q.l1Mode = 1; q.l1W = W1c2; q.l1b = bc1;
            q.l1Alo = Sp; q.l1Ahi = Sp + 1152; q.l1H = Sq;
            q.pA = Sp + 1152; q.pOut = out + (size_t)(t - 1) * I_;
            fused_step<<<544, 256, 0, stream>>>(q);
        }
        {
            StepArgs q = a;
            q.nL2 = 512; q.nL1 = 0; q.nProj = 0; q.nCopy = 0;
            q.l2Alo = Sq; q.l2Ahi = Sp + 1152; q.l2H = Sq + 1152;
            fused_step<<<512, 256, 0, stream>>>(q);
        }
    }

    // final: proj(79)
    {
        _Float16* Sl = S[1 + (((NST_ - 1 - T_) & 1) ^ 1)];
        StepArgs q = a;
        q.nL2 = 0; q.nL1 = 0; q.nProj = 32; q.nCopy = 0;
        q.pA = Sl + 1152; q.pOut = out + (size_t)(NST_ - 1) * I_;
        fused_step<<<32, 256, 0, stream>>>(q);
    }
}

// Round 9
// 4006.948 us; speedup vs baseline: 1.4849x; 1.4849x over previous
//
#include <hip/hip_runtime.h>

// TrajLSTM: 2-layer LSTM (H=1024), T=64 steps + 16 autoregressive. B=1024, I=64.
// fp16 MFMA GEMMs, fused LSTM-cell epilogue, fp16-MFMA out-proj.
//
// State rows (fp16, stride 2176): [h1(1024) | x(64) | pad(64) | h2(1024)],
// three buffers rotating by t%3; one fused main dispatch = {L2(t), L1(t+1),
// proj(t-1), xcopy(t+2)}. Future phase: composed L1' (proj folded into L1).
//
// Round 9: long barrier-free K-stretches (AITER-style), no split-K.
//  - Block stages a 64-row x 512-k A-panel (64 KB LDS) per stage; ONE barrier
//    pair per 16 k32-iterations (8 barriers/unit vs 32+ in r4-r7). Inside a
//    stretch: af from LDS (fine-grained lgkmcnt), bf global->VGPR depth-1
//    prefetch (fine-grained vmcnt(N), no block drains).
//  - 4 waves = 4 H-groups (no split-K, no combine barriers); wave tile
//    64b x 16H x 4 gates, acc 64 VGPR; total ~160 VGPR (no spill).
//  - XOR-granule swizzle for 1KB rows: phys = g ^ ((row&15)<<2); DMA stages
//    one row (1 KB) per global_load_lds wave-instr.
//  - RT=2 (32-row) variant for prologue/future dispatches -> 512 blocks, 2/CU.
//  - XCD weight pinning via bid%8 -> bh in {x, x+8} (2 MB W2-slice per XCD).

#define B_   1024
#define T_   64
#define I_   64
#define H_   1024
#define FUT_ 16
#define NST_ (T_ + FUT_)
#define SROW 2176

typedef _Float16 half8_t  __attribute__((ext_vector_type(8)));
typedef _Float16 half4_t  __attribute__((ext_vector_type(4)));
typedef float    float4_t __attribute__((ext_vector_type(4)));

typedef __attribute__((address_space(1))) const unsigned int g_u32;
typedef __attribute__((address_space(3))) unsigned int l_u32;

__device__ __forceinline__ void load_lds16(const _Float16* g, _Float16* l) {
    __builtin_amdgcn_global_load_lds((g_u32*)g, (l_u32*)l, 16, 0, 0);
}

__device__ __forceinline__ float sigmoid_f(float x) {
    x = fminf(fmaxf(x, -30.f), 30.f);
    return __fdividef(1.f, 1.f + __expf(-x));
}
__device__ __forceinline__ float tanh_f(float x) {
    x = fminf(fmaxf(x, -15.f), 15.f);
    float e = __expf(2.f * x);
    return 1.f - 2.f * __fdividef(1.f, e + 1.f);
}

// ---------------- one-time conversion / packing (r8, verified) -------------
// W1p:  [hgrp 64][kstep 36][gate 4][1KB]  (K=1152: Whh1 | Wih1 | pad0)
// W2p:  [hgrp 64][kstep 64][gate 4][1KB]  (K=2048: Wih2 | Whh2)
// W1c2: [hgrp 64][kstep 64][gate 4][1KB]  (K=2048: Whh1 | Wih1@Wlin)
// Wlp:  [hgrp 4 ][kstep 32][1KB]          (64 x 1024)
__global__ void convert_all(const float* __restrict__ x,
    const float* __restrict__ Wih1, const float* __restrict__ Whh1,
    const float* __restrict__ bih1, const float* __restrict__ bhh1,
    const float* __restrict__ Wih2, const float* __restrict__ Whh2,
    const float* __restrict__ bih2, const float* __restrict__ bhh2,
    const float* __restrict__ Wlin,
    _Float16* __restrict__ W1p, _Float16* __restrict__ W2p,
    _Float16* __restrict__ W1c2, _Float16* __restrict__ Wlp,
    _Float16* __restrict__ S0x, _Float16* __restrict__ S1x,
    float* __restrict__ b1, float* __restrict__ b2)
{
    size_t idx = (size_t)blockIdx.x * 256 + threadIdx.x;
    const size_t nc1  = 589824;    // 4096*1152/8
    const size_t nc2  = 1048576;   // 4096*2048/8
    const size_t nc2b = 524288;    // W1c2 low half
    const size_t nc3  = 8192;      // 64*1024/8
    const size_t nx   = 65536;     // B_*I_
    if (idx < nc1) {
        int c = (int)idx;
        int lane = c & 63, g = (c >> 6) & 3, rem = c >> 8;
        int j = rem % 36, hgrp = rem / 36;
        int row = (g << 10) + hgrp * 16 + (lane & 15);
        int kb = j * 32 + (lane >> 4) * 8;
        _Float16* o = &W1p[(size_t)c * 8];
        if (kb < 1024) {
            #pragma unroll
            for (int i = 0; i < 8; ++i) o[i] = (_Float16)Whh1[(size_t)row * 1024 + kb + i];
        } else if (kb < 1088) {
            #pragma unroll
            for (int i = 0; i < 8; ++i) o[i] = (_Float16)Wih1[row * 64 + (kb - 1024) + i];
        } else {
            #pragma unroll
            for (int i = 0; i < 8; ++i) o[i] = (_Float16)0.f;
        }
    } else if ((idx -= nc1) < nc2) {
        int c = (int)idx;
        int lane = c & 63, g = (c >> 6) & 3, rem = c >> 8;
        int j = rem & 63, hgrp = rem >> 6;
        int row = (g << 10) + hgrp * 16 + (lane & 15);
        int kb = j * 32 + (lane >> 4) * 8;
        _Float16* o = &W2p[(size_t)c * 8];
        if (kb < 1024) {
            #pragma unroll
            for (int i = 0; i < 8; ++i) o[i] = (_Float16)Wih2[(size_t)row * 1024 + kb + i];
        } else {
            #pragma unroll
            for (int i = 0; i < 8; ++i) o[i] = (_Float16)Whh2[(size_t)row * 1024 + kb - 1024 + i];
        }
    } else if ((idx -= nc2) < nc2b) {
        int c = (int)idx;
        int lane = c & 63, g = (c >> 6) & 3, rem = c >> 8;
        int j = rem & 31, hgrp = rem >> 5;
        int row = (g << 10) + hgrp * 16 + (lane & 15);
        int kb = j * 32 + (lane >> 4) * 8;
        _Float16* o = &W1c2[((((size_t)hgrp * 64 + j) * 4 + g) * 512) + lane * 8];
        #pragma unroll
        for (int i = 0; i < 8; ++i) o[i] = (_Float16)Whh1[(size_t)row * 1024 + kb + i];
    } else if ((idx -= nc2b) < nc3) {
        int c = (int)idx;
        int lane = c & 63, j = (c >> 6) & 31, hgrp = c >> 11;
        int row = hgrp * 16 + (lane & 15);
        int kb = j * 32 + (lane >> 4) * 8;
        _Float16* o = &Wlp[(size_t)c * 8];
        #pragma unroll
        for (int i = 0; i < 8; ++i) o[i] = (_Float16)Wlin[(size_t)row * 1024 + kb + i];
    } else if ((idx -= nc3) < nx) {
        int b = (int)(idx >> 6), i = (int)(idx & 63);
        S0x[(size_t)b * SROW + i] = (_Float16)x[(size_t)b * (T_ * I_) + i];
    } else if ((idx -= nx) < nx) {
        int b = (int)(idx >> 6), i = (int)(idx & 63);
        S1x[(size_t)b * SROW + i] = (_Float16)x[(size_t)b * (T_ * I_) + 64 + i];
    } else if ((idx -= nx) < 4096) {
        b1[idx] = bih1[idx] + bhh1[idx];
    } else if ((idx -= 4096) < 4096) {
        b2[idx] = bih2[idx] + bhh2[idx];
    }
}

// Composite = Wih1 @ Wlin (LDS-tiled), packed fp16 into W1c2 high half;
// blocks >= 1024 compute bc1 = b1 + Wih1 @ b_lin.  (r8, verified)
__global__ __launch_bounds__(256) void compose_tile(
    const float* __restrict__ Wih1, const float* __restrict__ Wlin,
    const float* __restrict__ blin, const float* __restrict__ b1in,
    _Float16* __restrict__ W1c2, float* __restrict__ bc1)
{
    if (blockIdx.x >= 1024) {
        int n = (blockIdx.x - 1024) * 256 + threadIdx.x;
        float s = b1in[n];
        for (int i = 0; i < 64; ++i) s += Wih1[n * 64 + i] * blin[i];
        bc1[n] = s;
        return;
    }
    __shared__ float sa[64][68];
    __shared__ float swl[64][68];
    const int tid = threadIdx.x;
    const int r0 = (blockIdx.x >> 4) * 64, c0 = (blockIdx.x & 15) * 64;
    #pragma unroll
    for (int t = 0; t < 16; ++t) {
        int e = tid + t * 256;
        int rr = e >> 6, cc = e & 63;
        sa[rr][cc]  = Wih1[(size_t)(r0 + rr) * 64 + cc];
        swl[rr][cc] = Wlin[(size_t)rr * 1024 + c0 + cc];
    }
    __syncthreads();
    const int tr = (tid >> 3) * 2, tc = (tid & 7) * 8;
    float acc[2][8] = {};
    for (int k = 0; k < 64; ++k) {
        float a0 = sa[tr][k], a1 = sa[tr + 1][k];
        #pragma unroll
        for (int j = 0; j < 8; ++j) {
            float wv = swl[k][tc + j];
            acc[0][j] += a0 * wv;
            acc[1][j] += a1 * wv;
        }
    }
    #pragma unroll
    for (int rr = 0; rr < 2; ++rr) {
        const int row = r0 + tr + rr;
        const int g = row >> 10, hgrp = (row & 1023) >> 4, lr16 = row & 15;
        const int hcol = c0 + tc;
        const int j = 32 + (hcol >> 5), lq = (hcol >> 3) & 3;
        half8_t v;
        #pragma unroll
        for (int e2 = 0; e2 < 8; ++e2) v[e2] = (_Float16)acc[rr][e2];
        *(half8_t*)(W1c2 + ((((size_t)hgrp * 64 + j) * 4 + g) * 512
                    + (lq * 16 + lr16) * 8)) = v;
    }
}

// ---------------- GEMM + fused LSTM cell -----------------------------------
// Block: M=RT*16 rows x 64 H-cols x 4 gates; 4 waves = 4 H-groups (no split-K).
// Stage M x 512-k A-panel; compute 16 k32-iters barrier-free per stage.
// LDS row = 512 halves (1 KB); swizzle phys granule = g ^ ((row&15)<<2).
template<int RT>
__device__ __forceinline__ void gemm_unit(_Float16* sbuf,
    const _Float16* __restrict__ A0, const _Float16* __restrict__ A1,
    const int kA, const int Ktot,
    const _Float16* __restrict__ Wp, const float* __restrict__ bias,
    float* __restrict__ cvec, _Float16* __restrict__ hdst, const int rb)
{
    const int tid = threadIdx.x, lane = tid & 63, w = tid >> 6;
    const int lr = lane & 15, lq = lane >> 4;
    constexpr int M = RT * 16;
    const int mt = rb >> 4, bh = rb & 15;
    const int hgrp = bh * 4 + w;           // XCD-pinned via rb%8
    const int m0 = mt * M;

    const _Float16* wbase = Wp + (size_t)hgrp * (Ktot >> 5) * 2048 + lane * 8;

    float4_t acc[4][RT];
    #pragma unroll
    for (int g = 0; g < 4; ++g)
        #pragma unroll
        for (int rt = 0; rt < RT; ++rt)
            #pragma unroll
            for (int e = 0; e < 4; ++e) acc[g][rt][e] = 0.f;

    int I = 0;
    for (int k0 = 0; k0 < Ktot; k0 += 512) {
        const int iters = (Ktot - k0 >= 512) ? 16 : ((Ktot - k0) >> 5);
        // ---- stage A-panel: wave stages rows [w*M/4, w*M/4 + M/4)
        const _Float16* base = (k0 < kA) ? (A0 + k0) : (A1 + (k0 - kA));
        #pragma unroll
        for (int r2 = 0; r2 < M / 4; ++r2) {
            const int row = w * (M / 4) + r2;
            load_lds16(base + (size_t)(m0 + row) * SROW
                           + ((lane ^ ((row & 15) << 2)) << 3),
                       sbuf + row * 512);
        }
        __syncthreads();   // DMA drain; panel visible

        // ---- 16-iter barrier-free stretch
        half8_t afc[RT], afn[RT], bfc[4], bfn[4];
        #pragma unroll
        for (int rt = 0; rt < RT; ++rt)
            afc[rt] = *(const half8_t*)&sbuf[(rt * 16 + lr) * 512
                        + ((0 ^ lr) << 5) + lq * 8];
        #pragma unroll
        for (int g = 0; g < 4; ++g)
            bfc[g] = *(const half8_t*)(wbase + (size_t)I * 2048 + g * 512);

        #pragma unroll 2
        for (int i = 0; i < iters; ++i) {
            if (i + 1 < iters) {
                #pragma unroll
                for (int rt = 0; rt < RT; ++rt)
                    afn[rt] = *(const half8_t*)&sbuf[(rt * 16 + lr) * 512
                                + (((i + 1) ^ lr) << 5) + lq * 8];
                #pragma unroll
                for (int g = 0; g < 4; ++g)
                    bfn[g] = *(const half8_t*)(wbase
                                + (size_t)(I + i + 1) * 2048 + g * 512);
            }
            #pragma unroll
            for (int g = 0; g < 4; ++g)
                #pragma unroll
                for (int rt = 0; rt < RT; ++rt)
                    acc[g][rt] = __builtin_amdgcn_mfma_f32_16x16x32_f16(
                        afc[rt], bfc[g], acc[g][rt], 0, 0, 0);
            #pragma unroll
            for (int rt = 0; rt < RT; ++rt) afc[rt] = afn[rt];
            #pragma unroll
            for (int g = 0; g < 4; ++g) bfc[g] = bfn[g];
        }
        I += iters;
        __syncthreads();   // readers done before panel overwrite
    }

    // ---- fused LSTM cell epilogue (lane holds i,f,g,o of same (b,j))
    const int j = hgrp * 16 + lr;
    const float bi = bias[j], bff = bias[1024 + j];
    const float bg = bias[2048 + j], bo = bias[3072 + j];
    #pragma unroll
    for (int rt = 0; rt < RT; ++rt) {
        #pragma unroll
        for (int e = 0; e < 4; ++e) {
            const int brow = m0 + rt * 16 + lq * 4 + e;
            float gi = sigmoid_f(acc[0][rt][e] + bi);
            float gf = sigmoid_f(acc[1][rt][e] + bff);
            float gv = tanh_f(acc[2][rt][e] + bg);
            float go = sigmoid_f(acc[3][rt][e] + bo);
            const size_t ci = (size_t)brow * 1024 + j;
            float cn = gf * cvec[ci] + gi * gv;
            cvec[ci] = cn;
            hdst[(size_t)brow * SROW + j] = (_Float16)(go * tanh_f(cn));
        }
    }
}

// out-proj: 64b x 64i, K=1024; wave = 16 i-cols; same staging scheme.
__device__ __forceinline__ void proj_unit(_Float16* sbuf,
    const _Float16* __restrict__ A, const _Float16* __restrict__ Wlp,
    const float* __restrict__ blin, float* __restrict__ outp, const int rb)
{
    const int tid = threadIdx.x, lane = tid & 63, w = tid >> 6;
    const int lr = lane & 15, lq = lane >> 4;
    const int m0 = rb * 64;
    const _Float16* wbase = Wlp + (size_t)w * 16384 + lane * 8;

    float4_t acc[4];
    #pragma unroll
    for (int rt = 0; rt < 4; ++rt)
        #pragma unroll
        for (int e = 0; e < 4; ++e) acc[rt][e] = 0.f;

    int I = 0;
    for (int k0 = 0; k0 < 1024; k0 += 512) {
        const _Float16* base = A + k0;
        #pragma unroll
        for (int r2 = 0; r2 < 16; ++r2) {
            const int row = w * 16 + r2;
            load_lds16(base + (size_t)(m0 + row) * SROW
                           + ((lane ^ ((row & 15) << 2)) << 3),
                       sbuf + row * 512);
        }
        __syncthreads();

        half8_t afc[4], afn[4], bfc, bfn;
        #pragma unroll
        for (int rt = 0; rt < 4; ++rt)
            afc[rt] = *(const half8_t*)&sbuf[(rt * 16 + lr) * 512
                        + ((0 ^ lr) << 5) + lq * 8];
        bfc = *(const half8_t*)(wbase + (size_t)I * 512);

        #pragma unroll 2
        for (int i = 0; i < 16; ++i) {
            if (i + 1 < 16) {
                #pragma unroll
                for (int rt = 0; rt < 4; ++rt)
                    afn[rt] = *(const half8_t*)&sbuf[(rt * 16 + lr) * 512
                                + (((i + 1) ^ lr) << 5) + lq * 8];
                bfn = *(const half8_t*)(wbase + (size_t)(I + i + 1) * 512);
            }
            #pragma unroll
            for (int rt = 0; rt < 4; ++rt)
                acc[rt] = __builtin_amdgcn_mfma_f32_16x16x32_f16(
                    afc[rt], bfc, acc[rt], 0, 0, 0);
            #pragma unroll
            for (int rt = 0; rt < 4; ++rt) afc[rt] = afn[rt];
            bfc = bfn;
        }
        I += 16;
        __syncthreads();
    }

    const int j = w * 16 + lr;
    const float bj = blin[j];
    #pragma unroll
    for (int rt = 0; rt < 4; ++rt)
        #pragma unroll
        for (int e = 0; e < 4; ++e) {
            const int brow = m0 + rt * 16 + lq * 4 + e;
            outp[(size_t)brow * (NST_ * I_) + j] = acc[rt][e] + bj;
        }
}

// ---------------- fused multi-role dispatch --------------------------------
struct StepArgs {
    int nL2, nL1, nProj, nCopy, rt2;
    const _Float16 *l2A0, *l2A1; _Float16* l2H;
    const _Float16 *l1A0, *l1A1; _Float16* l1H;
    const _Float16* l1W; const float* l1b; int l1K, l1kA;
    const _Float16* pA; float* pOut;
    const float* xsrc; _Float16* xdst;
    const _Float16 *W2p, *Wlp;
    const float *b2, *blin;
    float *c1, *c2;
};

__global__ __launch_bounds__(256, 2) void fused_step(StepArgs a) {
    __shared__ __align__(16) _Float16 sbuf[32768];   // 64 KB
    int bid = blockIdx.x;
    if (bid < a.nL2) {
        if (a.rt2) gemm_unit<2>(sbuf, a.l2A0, a.l2A1, 1024, 2048,
                                a.W2p, a.b2, a.c2, a.l2H, bid);
        else       gemm_unit<4>(sbuf, a.l2A0, a.l2A1, 1024, 2048,
                                a.W2p, a.b2, a.c2, a.l2H, bid);
    } else if ((bid -= a.nL2) < a.nL1) {
        if (a.rt2) gemm_unit<2>(sbuf, a.l1A0, a.l1A1, a.l1kA, a.l1K,
                                a.l1W, a.l1b, a.c1, a.l1H, bid);
        else       gemm_unit<4>(sbuf, a.l1A0, a.l1A1, a.l1kA, a.l1K,
                                a.l1W, a.l1b, a.c1, a.l1H, bid);
    } else if ((bid -= a.nL1) < a.nProj) {
        proj_unit(sbuf, a.pA, a.Wlp, a.blin, a.pOut, bid);
    } else if ((bid -= a.nProj) < a.nCopy) {
        // x(t+2) fp32 -> fp16 into state x-slot, float4-vectorized
        for (int k4 = bid * 256 + threadIdx.x; k4 < 16384; k4 += a.nCopy * 256) {
            int b = k4 >> 4, c4 = (k4 & 15) << 2;
            float4 v = *(const float4*)&a.xsrc[(size_t)b * (T_ * I_) + c4];
            half4_t hv = { (_Float16)v.x, (_Float16)v.y,
                           (_Float16)v.z, (_Float16)v.w };
            *(half4_t*)&a.xdst[(size_t)b * SROW + c4] = hv;
        }
    }
}

// ---------------------------------------------------------------------------
extern "C" void kernel_launch(void* const* d_in, const int* in_sizes, int n_in,
                              void* d_out, int out_size, void* d_ws, size_t ws_size,
                              hipStream_t stream) {
    (void)in_sizes; (void)n_in; (void)out_size; (void)ws_size;
    const float* x    = (const float*)d_in[0];
    const float* Wih1 = (const float*)d_in[1];
    const float* Whh1 = (const float*)d_in[2];
    const float* bih1 = (const float*)d_in[3];
    const float* bhh1 = (const float*)d_in[4];
    const float* Wih2 = (const float*)d_in[5];
    const float* Whh2 = (const float*)d_in[6];
    const float* bih2 = (const float*)d_in[7];
    const float* bhh2 = (const float*)d_in[8];
    const float* Wlin = (const float*)d_in[9];
    const float* blin = (const float*)d_in[10];
    float* out = (float*)d_out;

    char* p = (char*)d_ws;
    auto alloc = [&](size_t bytes) {
        char* r = p; p += (bytes + 255) & ~(size_t)255; return r;
    };
    _Float16* W1p  = (_Float16*)alloc((size_t)4096 * 1152 * 2);
    _Float16* W2p  = (_Float16*)alloc((size_t)4096 * 2048 * 2);
    _Float16* W1c2 = (_Float16*)alloc((size_t)4096 * 2048 * 2);
    _Float16* Wlp  = (_Float16*)alloc((size_t)64 * 1024 * 2);
    _Float16* S[3];
    for (int i = 0; i < 3; ++i) S[i] = (_Float16*)alloc((size_t)B_ * SROW * 2);
    float* c1  = (float*)alloc((size_t)B_ * H_ * 4);
    float* c2  = (float*)alloc((size_t)B_ * H_ * 4);
    float* b1  = (float*)alloc(4096 * 4);
    float* b2  = (float*)alloc(4096 * 4);
    float* bc1 = (float*)alloc(4096 * 4);

    for (int i = 0; i < 3; ++i)
        hipMemsetAsync(S[i], 0, (size_t)B_ * SROW * 2, stream);
    hipMemsetAsync(c1, 0, (size_t)B_ * H_ * 4, stream);
    hipMemsetAsync(c2, 0, (size_t)B_ * H_ * 4, stream);

    {
        const size_t total = 589824 + 1048576 + 524288 + 8192
                           + 65536 + 65536 + 8192;
        convert_all<<<(int)((total + 255) / 256), 256, 0, stream>>>(
            x, Wih1, Whh1, bih1, bhh1, Wih2, Whh2, bih2, bhh2, Wlin,
            W1p, W2p, W1c2, Wlp, S[0] + 1024, S[1] + 1024, b1, b2);
        compose_tile<<<1040, 256, 0, stream>>>(Wih1, Wlin, blin, b1, W1c2, bc1);
    }

    StepArgs a{};
    a.W2p = W2p; a.Wlp = Wlp; a.blin = blin;
    a.b2 = b2; a.c1 = c1; a.c2 = c2;
    a.l1W = W1p; a.l1b = b1; a.l1K = 1152; a.l1kA = 4096;

    // prologue: L1(0) alone (RT2, 512 blocks)
    {
        StepArgs q = a;
        q.nL2 = 0; q.nL1 = 512; q.nProj = 0; q.nCopy = 0; q.rt2 = 1;
        q.l1A0 = S[0]; q.l1A1 = S[0]; q.l1H = S[1];
        fused_step<<<512, 256, 0, stream>>>(q);
    }

    // main phase: D_t = {L2(t), L1(t+1), proj(t-1), xcopy(t+2)}  (RT4)
    for (int t = 0; t <= 62; ++t) {
        _Float16* Sp = S[t % 3];
        _Float16* Sq = S[(t + 1) % 3];
        _Float16* Sn = S[(t + 2) % 3];
        StepArgs q = a;
        q.nL2 = 256; q.nL1 = 256; q.rt2 = 0;
        q.nProj = (t >= 1) ? 16 : 0;
        q.nCopy = (t <= 61) ? 4 : 0;
        q.l2A0 = Sq; q.l2A1 = Sp + 1152; q.l2H = Sq + 1152;
        q.l1A0 = Sq; q.l1A1 = Sq; q.l1H = Sn;
        q.pA = Sp + 1152; q.pOut = out + (size_t)(t - 1) * I_;
        q.xsrc = x + (size_t)(t + 2) * I_; q.xdst = Sn + 1024;
        int grid = q.nL2 + q.nL1 + q.nProj + q.nCopy;
        fused_step<<<grid, 256, 0, stream>>>(q);
    }

    // t=63: {L2(63), proj(62)}
    {
        StepArgs q = a;
        q.nL2 = 256; q.nL1 = 0; q.nProj = 16; q.nCopy = 0; q.rt2 = 0;
        q.l2A0 = S[1]; q.l2A1 = S[0] + 1152; q.l2H = S[1] + 1152;
        q.pA = S[0] + 1152; q.pOut = out + (size_t)62 * I_;
        fused_step<<<272, 256, 0, stream>>>(q);
    }

    // future phase (composed L1'): per step t:
    //   D1 = {L1'(t): [h1(t-1)|h2(t-1)] @ W1c2 -> h1(t), proj(t-1)}  (RT2)
    //   D2 = {L2(t):  [h1(t)|h2(t-1)] -> h2(t)}                      (RT2)
    for (int t = T_; t < NST_; ++t) {
        _Float16* Sp = S[1 + ((t - T_) & 1)];
        _Float16* Sq = S[1 + (((t - T_) & 1) ^ 1)];
        {
            StepArgs q = a;
            q.nL2 = 0; q.nL1 = 512; q.nProj = 16; q.nCopy = 0; q.rt2 = 1;
            q.l1W = W1c2; q.l1b = bc1; q.l1K = 2048; q.l1kA = 1024;
            q.l1A0 = Sp; q.l1A1 = Sp + 1152; q.l1H = Sq;
            q.pA = Sp + 1152; q.pOut = out + (size_t)(t - 1) * I_;
            fused_step<<<528, 256, 0, stream>>>(q);
        }
        {
            StepArgs q = a;
            q.nL2 = 512; q.nL1 = 0; q.nProj = 0; q.nCopy = 0; q.rt2 = 1;
            q.l2A0 = Sq; q.l2A1 = Sp + 1152; q.l2H = Sq + 1152;
            fused_step<<<512, 256, 0, stream>>>(q);
        }
    }

    // final: proj(79)
    {
        _Float16* Sl = S[1 + (((NST_ - 1 - T_) & 1) ^ 1)];
        StepArgs q = a;
        q.nL2 = 0; q.nL1 = 0; q.nProj = 16; q.nCopy = 0; q.rt2 = 0;
        q.pA = Sl + 1152; q.pOut = out + (size_t)(NST_ - 1) * I_;
        fused_step<<<16, 256, 0, stream>>>(q);
    }
}

// Round 10
// 3281.026 us; speedup vs baseline: 1.8134x; 1.2212x over previous
//
#include <hip/hip_runtime.h>

// TrajLSTM: 2-layer LSTM (H=1024), T=64 steps + 16 autoregressive. B=1024, I=64.
// fp16 MFMA GEMMs, fused LSTM-cell epilogue, fp16-MFMA out-proj.
//
// State rows (fp16, stride 2176): [h1(1024) | x(64) | pad(64) | h2(1024)],
// three buffers rotating by t%3; one fused main dispatch = {L2(t), L1(t+1),
// proj(t-1), xcopy(t+2)}. Future phase: composed L1' (proj folded into L1),
// 2 dispatches/step.
//
// Round 10 = r7 body (best-known: m64 x BK128, dbuf 32 KB, ONE barrier/iter,
// verified-conflict-free XOR swizzle, global_load_lds staging, bf depth-1
// prefetch, XCD weight pinning) with:
//  - __launch_bounds__(256,4): 4 blocks/CU (128 KB LDS of 160), grid 1072
//    ~= 4.2/CU -> blocks de-phase each other's barrier drains.
//  - split-K combine in ONE round (32 KB scratch): 2 barriers instead of 5.
//  - fast compose_tile (r8-verified) instead of 61us scalar compose_pack.

#define B_   1024
#define T_   64
#define I_   64
#define H_   1024
#define FUT_ 16
#define NST_ (T_ + FUT_)
#define SROW 2176

typedef _Float16 half8_t  __attribute__((ext_vector_type(8)));
typedef float    float4_t __attribute__((ext_vector_type(4)));

typedef __attribute__((address_space(1))) const unsigned int g_u32;
typedef __attribute__((address_space(3))) unsigned int l_u32;

__device__ __forceinline__ void load_lds16(const _Float16* g, _Float16* l) {
    __builtin_amdgcn_global_load_lds((g_u32*)g, (l_u32*)l, 16, 0, 0);
}

__device__ __forceinline__ float sigmoid_f(float x) {
    x = fminf(fmaxf(x, -30.f), 30.f);
    return __fdividef(1.f, 1.f + __expf(-x));
}
__device__ __forceinline__ float tanh_f(float x) {
    x = fminf(fmaxf(x, -15.f), 15.f);
    float e = __expf(2.f * x);
    return 1.f - 2.f * __fdividef(1.f, e + 1.f);
}

// ---------------- one-time conversion / packing ----------------------------
// W1p:  [hgrp 64][kstep 36][gate 4][1KB]  (K=1152: Whh1 | Wih1 | pad0)
// W2p:  [hgrp 64][kstep 64][gate 4][1KB]  (K=2048: Wih2 | Whh2)
// W1c2: [hgrp 64][kstep 64][gate 4][1KB]  (K=2048: Whh1 | Wih1@Wlin);
//       low half (j<32) here, high half by compose_tile.
// Wlp:  [hgrp 4 ][kstep 32][1KB]          (64 x 1024)
__global__ void convert_all(const float* __restrict__ x,
    const float* __restrict__ Wih1, const float* __restrict__ Whh1,
    const float* __restrict__ bih1, const float* __restrict__ bhh1,
    const float* __restrict__ Wih2, const float* __restrict__ Whh2,
    const float* __restrict__ bih2, const float* __restrict__ bhh2,
    const float* __restrict__ Wlin,
    _Float16* __restrict__ W1p, _Float16* __restrict__ W2p,
    _Float16* __restrict__ W1c2, _Float16* __restrict__ Wlp,
    _Float16* __restrict__ S0x, _Float16* __restrict__ S1x,
    float* __restrict__ b1, float* __restrict__ b2)
{
    size_t idx = (size_t)blockIdx.x * 256 + threadIdx.x;
    const size_t nc1  = 589824;    // 4096*1152/8
    const size_t nc2  = 1048576;   // 4096*2048/8
    const size_t nc2b = 524288;    // W1c2 low half
    const size_t nc3  = 8192;      // 64*1024/8
    const size_t nx   = 65536;     // B_*I_
    if (idx < nc1) {
        int c = (int)idx;
        int lane = c & 63, g = (c >> 6) & 3, rem = c >> 8;
        int j = rem % 36, hgrp = rem / 36;
        int row = (g << 10) + hgrp * 16 + (lane & 15);
        int kb = j * 32 + (lane >> 4) * 8;
        _Float16* o = &W1p[(size_t)c * 8];
        if (kb < 1024) {
            #pragma unroll
            for (int i = 0; i < 8; ++i) o[i] = (_Float16)Whh1[(size_t)row * 1024 + kb + i];
        } else if (kb < 1088) {
            #pragma unroll
            for (int i = 0; i < 8; ++i) o[i] = (_Float16)Wih1[row * 64 + (kb - 1024) + i];
        } else {
            #pragma unroll
            for (int i = 0; i < 8; ++i) o[i] = (_Float16)0.f;
        }
    } else if ((idx -= nc1) < nc2) {
        int c = (int)idx;
        int lane = c & 63, g = (c >> 6) & 3, rem = c >> 8;
        int j = rem & 63, hgrp = rem >> 6;
        int row = (g << 10) + hgrp * 16 + (lane & 15);
        int kb = j * 32 + (lane >> 4) * 8;
        _Float16* o = &W2p[(size_t)c * 8];
        if (kb < 1024) {
            #pragma unroll
            for (int i = 0; i < 8; ++i) o[i] = (_Float16)Wih2[(size_t)row * 1024 + kb + i];
        } else {
            #pragma unroll
            for (int i = 0; i < 8; ++i) o[i] = (_Float16)Whh2[(size_t)row * 1024 + kb - 1024 + i];
        }
    } else if ((idx -= nc2) < nc2b) {
        int c = (int)idx;
        int lane = c & 63, g = (c >> 6) & 3, rem = c >> 8;
        int j = rem & 31, hgrp = rem >> 5;
        int row = (g << 10) + hgrp * 16 + (lane & 15);
        int kb = j * 32 + (lane >> 4) * 8;
        _Float16* o = &W1c2[((((size_t)hgrp * 64 + j) * 4 + g) * 512) + lane * 8];
        #pragma unroll
        for (int i = 0; i < 8; ++i) o[i] = (_Float16)Whh1[(size_t)row * 1024 + kb + i];
    } else if ((idx -= nc2b) < nc3) {
        int c = (int)idx;
        int lane = c & 63, j = (c >> 6) & 31, hgrp = c >> 11;
        int row = hgrp * 16 + (lane & 15);
        int kb = j * 32 + (lane >> 4) * 8;
        _Float16* o = &Wlp[(size_t)c * 8];
        #pragma unroll
        for (int i = 0; i < 8; ++i) o[i] = (_Float16)Wlin[(size_t)row * 1024 + kb + i];
    } else if ((idx -= nc3) < nx) {
        int b = (int)(idx >> 6), i = (int)(idx & 63);
        S0x[(size_t)b * SROW + i] = (_Float16)x[(size_t)b * (T_ * I_) + i];
    } else if ((idx -= nx) < nx) {
        int b = (int)(idx >> 6), i = (int)(idx & 63);
        S1x[(size_t)b * SROW + i] = (_Float16)x[(size_t)b * (T_ * I_) + 64 + i];
    } else if ((idx -= nx) < 4096) {
        b1[idx] = bih1[idx] + bhh1[idx];
    } else if ((idx -= 4096) < 4096) {
        b2[idx] = bih2[idx] + bhh2[idx];
    }
}

// Composite = Wih1 @ Wlin (LDS-tiled), packed fp16 into W1c2 high half;
// blocks >= 1024 compute bc1 = b1 + Wih1 @ b_lin.  (r8, verified)
__global__ __launch_bounds__(256) void compose_tile(
    const float* __restrict__ Wih1, const float* __restrict__ Wlin,
    const float* __restrict__ blin, const float* __restrict__ b1in,
    _Float16* __restrict__ W1c2, float* __restrict__ bc1)
{
    if (blockIdx.x >= 1024) {
        int n = (blockIdx.x - 1024) * 256 + threadIdx.x;
        float s = b1in[n];
        for (int i = 0; i < 64; ++i) s += Wih1[n * 64 + i] * blin[i];
        bc1[n] = s;
        return;
    }
    __shared__ float sa[64][68];
    __shared__ float swl[64][68];
    const int tid = threadIdx.x;
    const int r0 = (blockIdx.x >> 4) * 64, c0 = (blockIdx.x & 15) * 64;
    #pragma unroll
    for (int t = 0; t < 16; ++t) {
        int e = tid + t * 256;
        int rr = e >> 6, cc = e & 63;
        sa[rr][cc]  = Wih1[(size_t)(r0 + rr) * 64 + cc];
        swl[rr][cc] = Wlin[(size_t)rr * 1024 + c0 + cc];
    }
    __syncthreads();
    const int tr = (tid >> 3) * 2, tc = (tid & 7) * 8;
    float acc[2][8] = {};
    for (int k = 0; k < 64; ++k) {
        float a0 = sa[tr][k], a1 = sa[tr + 1][k];
        #pragma unroll
        for (int j = 0; j < 8; ++j) {
            float wv = swl[k][tc + j];
            acc[0][j] += a0 * wv;
            acc[1][j] += a1 * wv;
        }
    }
    #pragma unroll
    for (int rr = 0; rr < 2; ++rr) {
        const int row = r0 + tr + rr;
        const int g = row >> 10, hgrp = (row & 1023) >> 4, lr16 = row & 15;
        const int hcol = c0 + tc;
        const int j = 32 + (hcol >> 5), lq = (hcol >> 3) & 3;
        half8_t v;
        #pragma unroll
        for (int e2 = 0; e2 < 8; ++e2) v[e2] = (_Float16)acc[rr][e2];
        *(half8_t*)(W1c2 + ((((size_t)hgrp * 64 + j) * 4 + g) * 512
                    + (lq * 16 + lr16) * 8)) = v;
    }
}

// ---------------- GEMM + fused LSTM cell -----------------------------------
// Block tile: 64 batch x 32 H x 4 gates; 4 waves = 2 hw (H) x 2 kh (split-K).
// sAb: 2 x (64 rows x 128 halves) = 32 KB; granule swizzle p = g ^ (row&15)
// (verified conflict-free r4/r5). One barrier per K-iter (dbuf).
__device__ __forceinline__ void gemm_body(_Float16* sAb,
    const _Float16* __restrict__ Alo, const _Float16* __restrict__ Ahi,
    const _Float16* __restrict__ Wp, const int iters, const int Ksh,
    const float* __restrict__ bias, float* __restrict__ cvec,
    _Float16* __restrict__ hdst, const int unit)
{
    const int tid = threadIdx.x;
    const int lane = tid & 63, w = tid >> 6;
    const int hw = w & 1, kh = w >> 1;
    const int lr = lane & 15, lq = lane >> 4;
    const int ht = ((unit & 7) << 2) | ((unit >> 3) & 3);   // XCD-pinned H tile
    const int mt = unit >> 5;                                // 0..15
    const int h0 = ht * 32, m0 = mt * 64;
    const int hgrp = ht * 2 + hw;

    const char* wptr = (const char*)Wp
        + ((size_t)hgrp * (2 * Ksh) + (size_t)kh * Ksh) * 4096
        + (size_t)lane * 16;

    // staging: round s (0..3): thread t -> row (t>>4)+s*16, phys granule t&15;
    // logical granule gg = (t&15) ^ (row&15) (s-invariant).
    const int srow0 = tid >> 4, pg = tid & 15;
    const int gg = pg ^ (srow0 & 15);
    const _Float16* asrc = (gg < 8 ? Alo : Ahi) + (gg & 7) * 8
                         + (size_t)(m0 + srow0) * SROW;

    // af read offset (halves): row*128 + ((kh*8 + ks*4 + lq) ^ (row&15))*8
    const int ag0 = ((kh * 8 + lq) ^ lr) * 8;
    const int ag1 = ((kh * 8 + 4 + lq) ^ lr) * 8;

    float4_t acc[4][4];
    #pragma unroll
    for (int g = 0; g < 4; ++g)
        #pragma unroll
        for (int rt = 0; rt < 4; ++rt)
            #pragma unroll
            for (int e = 0; e < 4; ++e) acc[g][rt][e] = 0.f;

    half8_t bfc[8], bfn[8];
    #pragma unroll
    for (int q = 0; q < 8; ++q)
        bfc[q] = *(const half8_t*)(wptr + q * 1024);

    // prologue DMA for iter 0 into buf0
    #pragma unroll
    for (int s = 0; s < 4; ++s)
        load_lds16(asrc + (size_t)s * 16 * SROW, sAb + tid * 8 + s * 2048);

    for (int i = 0; i < iters; ++i) {
        __syncthreads();   // vmcnt(0) drain: DMA(i) + bf(i) complete
        _Float16* cur = sAb + (i & 1) * 8192;
        if (i + 1 < iters) {
            _Float16* nxt = sAb + ((i + 1) & 1) * 8192;
            const _Float16* an = asrc + (size_t)(i + 1) * 64;
            #pragma unroll
            for (int s = 0; s < 4; ++s)
                load_lds16(an + (size_t)s * 16 * SROW, nxt + tid * 8 + s * 2048);
            const char* wn = wptr + 8192;
            #pragma unroll
            for (int q = 0; q < 8; ++q)
                bfn[q] = *(const half8_t*)(wn + q * 1024);
        }
        #pragma unroll
        for (int ks = 0; ks < 2; ++ks) {
            const int ag = ks ? ag1 : ag0;
            #pragma unroll
            for (int rt = 0; rt < 4; ++rt) {
                half8_t af = *(const half8_t*)&cur[(rt * 16 + lr) * 128 + ag];
                #pragma unroll
                for (int g = 0; g < 4; ++g)
                    acc[g][rt] = __builtin_amdgcn_mfma_f32_16x16x32_f16(
                        af, bfc[ks * 4 + g], acc[g][rt], 0, 0, 0);
            }
        }
        wptr += 8192;
        #pragma unroll
        for (int q = 0; q < 8; ++q) bfc[q] = bfn[q];
    }
    __syncthreads();   // K-loop reads done before scratch overwrite

    // split-K combine: ONE round, all 4 gates (32 KB scratch)
    float* scr = (float*)sAb;
    if (kh == 1) {
        #pragma unroll
        for (int g = 0; g < 4; ++g)
            #pragma unroll
            for (int rt = 0; rt < 4; ++rt) {
                int slot = ((hw * 4 + g) * 4 + rt) * 64 + lane;
                *(float4_t*)&scr[slot * 4] = acc[g][rt];
            }
    }
    __syncthreads();
    if (kh != 0) return;
    #pragma unroll
    for (int g = 0; g < 4; ++g)
        #pragma unroll
        for (int rt = 0; rt < 4; ++rt) {
            int slot = ((hw * 4 + g) * 4 + rt) * 64 + lane;
            acc[g][rt] += *(const float4_t*)&scr[slot * 4];
        }

    const int j = h0 + hw * 16 + lr;
    const float bi = bias[j], bff = bias[1024 + j];
    const float bg = bias[2048 + j], bo = bias[3072 + j];
    #pragma unroll
    for (int rt = 0; rt < 4; ++rt) {
        #pragma unroll
        for (int e = 0; e < 4; ++e) {
            const int brow = m0 + rt * 16 + lq * 4 + e;
            float gi = sigmoid_f(acc[0][rt][e] + bi);
            float gf = sigmoid_f(acc[1][rt][e] + bff);
            float gv = tanh_f(acc[2][rt][e] + bg);
            float go = sigmoid_f(acc[3][rt][e] + bo);
            const size_t ci = (size_t)brow * 1024 + j;
            float cn = gf * cvec[ci] + gi * gv;
            cvec[ci] = cn;
            hdst[(size_t)brow * SROW + j] = (_Float16)(go * tanh_f(cn));
        }
    }
}

// out-proj: 64 batch x 32 i tile, K=1024 fp16 MFMA (16 KB staging buffer).
__device__ __forceinline__ void proj_body(_Float16* sA,
    const _Float16* __restrict__ A, const _Float16* __restrict__ Wp,
    const float* __restrict__ blin, float* __restrict__ outp,
    const int unit)
{
    const int iters = 8;
    const int tid = threadIdx.x;
    const int lane = tid & 63, w = tid >> 6;
    const int hw = w & 1, kh = w >> 1;
    const int lr = lane & 15, lq = lane >> 4;
    const int ht = unit & 1, mt = unit >> 1;
    const int h0 = ht * 32, m0 = mt * 64;
    const int hgrp = ht * 2 + hw;

    const char* wptr = (const char*)Wp
        + ((size_t)hgrp * 32 + (size_t)kh * 16) * 1024 + (size_t)lane * 16;

    const int srow0 = tid >> 4, pg = tid & 15;
    const int gg = pg ^ (srow0 & 15);
    const _Float16* asrc = A + (size_t)(gg >> 3) * 512 + (gg & 7) * 8
                         + (size_t)(m0 + srow0) * SROW;
    _Float16* ldst = sA + tid * 8;
    const int ag0 = ((kh * 8 + lq) ^ lr) * 8;
    const int ag1 = ((kh * 8 + 4 + lq) ^ lr) * 8;

    float4_t acc[4];
    #pragma unroll
    for (int rt = 0; rt < 4; ++rt)
        #pragma unroll
        for (int e = 0; e < 4; ++e) acc[rt][e] = 0.f;

    half8_t b0 = *(const half8_t*)(wptr);
    half8_t b1v = *(const half8_t*)(wptr + 1024);
    for (int i = 0; i < iters; ++i) {
        #pragma unroll
        for (int s = 0; s < 4; ++s)
            load_lds16(asrc + (size_t)s * 16 * SROW + (size_t)i * 64,
                       ldst + s * 2048);
        __syncthreads();
        half8_t n0, n1;
        if (i + 1 < iters) {
            n0 = *(const half8_t*)(wptr + 2048);
            n1 = *(const half8_t*)(wptr + 3072);
        }
        half8_t af;
        #pragma unroll
        for (int rt = 0; rt < 4; ++rt) {
            af = *(const half8_t*)&sA[(rt * 16 + lr) * 128 + ag0];
            acc[rt] = __builtin_amdgcn_mfma_f32_16x16x32_f16(af, b0, acc[rt], 0, 0, 0);
        }
        #pragma unroll
        for (int rt = 0; rt < 4; ++rt) {
            af = *(const half8_t*)&sA[(rt * 16 + lr) * 128 + ag1];
            acc[rt] = __builtin_amdgcn_mfma_f32_16x16x32_f16(af, b1v, acc[rt], 0, 0, 0);
        }
        __syncthreads();
        wptr += 2048;
        b0 = n0; b1v = n1;
    }

    float* scr = (float*)sA;
    if (kh == 1) {
        #pragma unroll
        for (int rt = 0; rt < 4; ++rt) {
            int slot = (hw * 4 + rt) * 64 + lane;
            *(float4_t*)&scr[slot * 4] = acc[rt];
        }
    }
    __syncthreads();
    if (kh != 0) return;
    #pragma unroll
    for (int rt = 0; rt < 4; ++rt) {
        int slot = (hw * 4 + rt) * 64 + lane;
        acc[rt] += *(const float4_t*)&scr[slot * 4];
    }

    const int j = h0 + hw * 16 + lr;
    const float bj = blin[j];
    #pragma unroll
    for (int rt = 0; rt < 4; ++rt) {
        #pragma unroll
        for (int e = 0; e < 4; ++e) {
            const int brow = m0 + rt * 16 + lq * 4 + e;
            outp[(size_t)brow * (NST_ * I_) + j] = acc[rt][e] + bj;
        }
    }
}

// ---------------- fused multi-role dispatch --------------------------------
struct StepArgs {
    int nL2, nL1, nProj, nCopy, l1Mode;
    const _Float16 *l2Alo, *l2Ahi; _Float16* l2H;
    const _Float16 *l1Alo, *l1Ahi; _Float16* l1H;
    const _Float16* l1W; const float* l1b;
    const _Float16* pA; float* pOut;
    const float* xsrc; _Float16* xdst;
    const _Float16 *W2p, *Wlp;
    const float *b2, *blin;
    float *c1, *c2;
};

__global__ __launch_bounds__(256, 4) void fused_step(StepArgs a) {
    __shared__ __align__(16) _Float16 sA[16384];   // 32 KB
    int bid = blockIdx.x;
    if (bid < a.nL2) {
        gemm_body(sA, a.l2Alo, a.l2Ahi, a.W2p, 16, 32, a.b2, a.c2, a.l2H, bid);
    } else if ((bid -= a.nL2) < a.nL1) {
        if (a.l1Mode)
            gemm_body(sA, a.l1Alo, a.l1Ahi, a.l1W, 16, 32, a.l1b, a.c1, a.l1H, bid);
        else
            gemm_body(sA, a.l1Alo, a.l1Ahi, a.l1W, 9, 18, a.l1b, a.c1, a.l1H, bid);
    } else if ((bid -= a.nL1) < a.nProj) {
        proj_body(sA, a.pA, a.Wlp, a.blin, a.pOut, bid);
    } else {
        bid -= a.nProj;
        int base = bid * 256 + threadIdx.x;
        for (int k = base; k < B_ * I_; k += a.nCopy * 256) {
            int b = k >> 6, i = k & 63;
            a.xdst[(size_t)b * SROW + i] = (_Float16)a.xsrc[(size_t)b * (T_ * I_) + i];
        }
    }
}

// ---------------------------------------------------------------------------
extern "C" void kernel_launch(void* const* d_in, const int* in_sizes, int n_in,
                              void* d_out, int out_size, void* d_ws, size_t ws_size,
                              hipStream_t stream) {
    (void)in_sizes; (void)n_in; (void)out_size; (void)ws_size;
    const float* x    = (const float*)d_in[0];
    const float* Wih1 = (const float*)d_in[1];
    const float* Whh1 = (const float*)d_in[2];
    const float* bih1 = (const float*)d_in[3];
    const float* bhh1 = (const float*)d_in[4];
    const float* Wih2 = (const float*)d_in[5];
    const float* Whh2 = (const float*)d_in[6];
    const float* bih2 = (const float*)d_in[7];
    const float* bhh2 = (const float*)d_in[8];
    const float* Wlin = (const float*)d_in[9];
    const float* blin = (const float*)d_in[10];
    float* out = (float*)d_out;

    char* p = (char*)d_ws;
    auto alloc = [&](size_t bytes) {
        char* r = p; p += (bytes + 255) & ~(size_t)255; return r;
    };
    _Float16* W1p  = (_Float16*)alloc((size_t)4096 * 1152 * 2);
    _Float16* W2p  = (_Float16*)alloc((size_t)4096 * 2048 * 2);
    _Float16* W1c2 = (_Float16*)alloc((size_t)4096 * 2048 * 2);
    _Float16* Wlp  = (_Float16*)alloc((size_t)64 * 1024 * 2);
    _Float16* S[3];
    for (int i = 0; i < 3; ++i) S[i] = (_Float16*)alloc((size_t)B_ * SROW * 2);
    float* c1  = (float*)alloc((size_t)B_ * H_ * 4);
    float* c2  = (float*)alloc((size_t)B_ * H_ * 4);
    float* b1  = (float*)alloc(4096 * 4);
    float* b2  = (float*)alloc(4096 * 4);
    float* bc1 = (float*)alloc(4096 * 4);

    for (int i = 0; i < 3; ++i)
        hipMemsetAsync(S[i], 0, (size_t)B_ * SROW * 2, stream);
    hipMemsetAsync(c1, 0, (size_t)B_ * H_ * 4, stream);
    hipMemsetAsync(c2, 0, (size_t)B_ * H_ * 4, stream);

    {
        const size_t total = 589824 + 1048576 + 524288 + 8192
                           + 65536 + 65536 + 8192;
        convert_all<<<(int)((total + 255) / 256), 256, 0, stream>>>(
            x, Wih1, Whh1, bih1, bhh1, Wih2, Whh2, bih2, bhh2, Wlin,
            W1p, W2p, W1c2, Wlp, S[0] + 1024, S[1] + 1024, b1, b2);
        compose_tile<<<1040, 256, 0, stream>>>(Wih1, Wlin, blin, b1, W1c2, bc1);
    }

    StepArgs a{};
    a.W2p = W2p; a.Wlp = Wlp; a.blin = blin;
    a.b2 = b2; a.c1 = c1; a.c2 = c2;
    a.l1W = W1p; a.l1b = b1; a.l1Mode = 0;

    // prologue: L1(0) alone (reads S[0] = [0|x(0)], writes h1(0) -> S[1])
    {
        StepArgs q = a;
        q.nL2 = 0; q.nL1 = 512; q.nProj = 0; q.nCopy = 0;
        q.l1Alo = S[0]; q.l1Ahi = S[0] + 576; q.l1H = S[1];
        fused_step<<<512, 256, 0, stream>>>(q);
    }

    // main phase: D_t = {L2(t), L1(t+1), proj(t-1), xcopy(t+2)}
    for (int t = 0; t <= 62; ++t) {
        _Float16* Sp = S[t % 3];
        _Float16* Sq = S[(t + 1) % 3];
        _Float16* Sn = S[(t + 2) % 3];
        StepArgs q = a;
        q.nL2 = 512; q.nL1 = 512;
        q.nProj = (t >= 1) ? 32 : 0;
        q.nCopy = (t <= 61) ? 16 : 0;
        q.l2Alo = Sq; q.l2Ahi = Sp + 1152; q.l2H = Sq + 1152;
        q.l1Alo = Sq; q.l1Ahi = Sq + 576; q.l1H = Sn;
        q.pA = Sp + 1152; q.pOut = out + (size_t)(t - 1) * I_;
        q.xsrc = x + (size_t)(t + 2) * I_; q.xdst = Sn + 1024;
        int grid = q.nL2 + q.nL1 + q.nProj + q.nCopy;
        fused_step<<<grid, 256, 0, stream>>>(q);
    }

    // t=63: {L2(63), proj(62)}
    {
        StepArgs q = a;
        q.nL2 = 512; q.nL1 = 0; q.nProj = 32; q.nCopy = 0;
        q.l2Alo = S[1]; q.l2Ahi = S[0] + 1152; q.l2H = S[1] + 1152;
        q.pA = S[0] + 1152; q.pOut = out + (size_t)62 * I_;
        fused_step<<<544, 256, 0, stream>>>(q);
    }

    // future phase (composed L1'): per step t:
    //   D1 = {L1'(t): [h1(t-1)|h2(t-1)] @ W1c2 -> h1(t), proj(t-1)}
    //   D2 = {L2(t):  [h1(t)|h2(t-1)] -> h2(t)}
    for (int t = T_; t < NST_; ++t) {
        _Float16* Sp = S[1 + ((t - T_) & 1)];
        _Float16* Sq = S[1 + (((t - T_) & 1) ^ 1)];
        {
            StepArgs q = a;
            q.nL2 = 0; q.nL1 = 512; q.nProj = 32; q.nCopy = 0;
            q.l1Mode = 1; q.l1W = W1c2; q.l1b = bc1;
            q.l1Alo = Sp; q.l1Ahi = Sp + 1152; q.l1H = Sq;
            q.pA = Sp + 1152; q.pOut = out + (size_t)(t - 1) * I_;
            fused_step<<<544, 256, 0, stream>>>(q);
        }
        {
            StepArgs q = a;
            q.nL2 = 512; q.nL1 = 0; q.nProj = 0; q.nCopy = 0;
            q.l2Alo = Sq; q.l2Ahi = Sp + 1152; q.l2H = Sq + 1152;
            fused_step<<<512, 256, 0, stream>>>(q);
        }
    }

    // final: proj(79)
    {
        _Float16* Sl = S[1 + (((NST_ - 1 - T_) & 1) ^ 1)];
        StepArgs q = a;
        q.nL2 = 0; q.nL1 = 0; q.nProj = 32; q.nCopy = 0;
        q.pA = Sl + 1152; q.pOut = out + (size_t)(NST_ - 1) * I_;
        fused_step<<<32, 256, 0, stream>>>(q);
    }
}